// Round 2
// baseline (919.263 us; speedup 1.0000x reference)
//
#include <hip/hip_runtime.h>
#include <cstdint>
#include <cstddef>

typedef unsigned short u16;
typedef unsigned int   u32;

#define D_MODEL 1024
#define D_INNER 2048
#define BATCH   8
#define TSEQ    2048
#define MROWS   (BATCH*TSEQ)      // 16384 rows for all GEMMs
#define CHUNK   32
#define NCHUNK  (TSEQ/CHUNK)      // 64
#define EDIM    (BATCH*D_INNER)   // 16384 scan lanes

typedef float  f32x4  __attribute__((ext_vector_type(4)));
typedef __bf16 bf16x8 __attribute__((ext_vector_type(8)));
typedef short  s16x8  __attribute__((ext_vector_type(8)));

__device__ __forceinline__ float bf2f(u16 u){ return __builtin_bit_cast(float, (u32)u << 16); }
__device__ __forceinline__ u16 f2bf(float f){
  u32 u = __builtin_bit_cast(u32, f);
  u += 0x7fffu + ((u >> 16) & 1u);
  return (u16)(u >> 16);
}
__device__ __forceinline__ float sigm(float x){ return 1.0f/(1.0f + __expf(-x)); }

__device__ __forceinline__ void gld16(const u16* g, u16* l){
  __builtin_amdgcn_global_load_lds((const __attribute__((address_space(1))) void*)g,
                                   (__attribute__((address_space(3))) void*)l, 16, 0, 0);
}

__device__ __forceinline__ s16x8 cvt8(const float* s){
  float4 u0 = *(const float4*)s;
  float4 u1 = *(const float4*)(s + 4);
  s16x8 p;
  p[0]=(short)f2bf(u0.x); p[1]=(short)f2bf(u0.y);
  p[2]=(short)f2bf(u0.z); p[3]=(short)f2bf(u0.w);
  p[4]=(short)f2bf(u1.x); p[5]=(short)f2bf(u1.y);
  p[6]=(short)f2bf(u1.z); p[7]=(short)f2bf(u1.w);
  return p;
}

// ---------------------------------------------------------------------------
// C = A (M x K) * Bt^T (Bt is N x K row-major f32, converted in staging),
// 128x128 tile, 4 waves (2x2), each wave 64x64 via 4x4 frags of
// mfma_f32_16x16x32_bf16.
// MODE 0: in_proj  — A = x f32, rows (b,t)->(t,b), epilogue silu, bf16 out
// MODE 1: alpha    — A bf16, epilogue sigmoid(acc + bias), bf16 out
// MODE 2: v        — A bf16, epilogue acc + bias, bf16 out
// MODE 3: out_proj — A bf16, rows (t,b)->(b,t), f32 out
// ---------------------------------------------------------------------------
template<int MODE, int K, int N>
__global__ __launch_bounds__(256) void gemm_bt(
    const void* __restrict__ Ap, const float* __restrict__ Btw,
    const float* __restrict__ bias, void* __restrict__ Cout)
{
  __shared__ __align__(16) u16 sA[128*32];
  __shared__ __align__(16) u16 sB[128*32];
  const int tid = threadIdx.x;
  const int bm = blockIdx.x, bn = blockIdx.y;
  const int w = tid >> 6, lane = tid & 63;
  const int wr = w >> 1, wc = w & 1;
  const int l15 = lane & 15, kg = lane >> 4;

  // staging: thread covers LDS u16 slot tid*8 (+2048 for the second half-tile)
  const int r0   = tid >> 2;        // tile row 0..63 (+64 for issue 1)
  const int koff = (tid & 3) * 8;   // k element offset within 32-wide K step

  int ga[2];
  #pragma unroll
  for (int i = 0; i < 2; ++i){
    int mc = bm*128 + r0 + i*64;
    if (MODE == 0)      ga[i] = (mc & 7) * TSEQ + (mc >> 3);          // C row (t,b) -> x row (b,t)
    else if (MODE == 3) ga[i] = (mc & (TSEQ-1)) * BATCH + (mc >> 11); // C row (b,t) -> outs row (t,b)
    else                ga[i] = mc;
  }

  const u16*   Ab = (const u16*)Ap;    // MODE 1,2,3 (bf16)
  const float* Af = (const float*)Ap;  // MODE 0 (f32)

  // wave-uniform LDS dest bases for global_load_lds (u16 units)
  u16* la[2] = { sA + w*512, sA + 2048 + w*512 };
  // per-thread ds_write slots (same mapping as gld16's base+lane*16B)
  u16* ldsA = sA + tid*8;
  u16* ldsB = sB + tid*8;

  const float* pbf[2];
  #pragma unroll
  for (int i = 0; i < 2; ++i)
    pbf[i] = Btw + (size_t)(bn*128 + r0 + i*64) * K + koff;

  f32x4 acc[4][4] = {};

  for (int kt = 0; kt < K/32; ++kt){
    __syncthreads();                       // prior ds_reads done before overwrite
    // ---- A staging ----
    if constexpr (MODE != 0){
      gld16(Ab + (size_t)ga[0]*K + koff + kt*32, la[0]);
      gld16(Ab + (size_t)ga[1]*K + koff + kt*32, la[1]);
    } else {
      #pragma unroll
      for (int i = 0; i < 2; ++i)
        *(s16x8*)(ldsA + i*2048) = cvt8(Af + (size_t)ga[i]*K + koff + kt*32);
    }
    // ---- B staging (f32 weights -> bf16) ----
    #pragma unroll
    for (int i = 0; i < 2; ++i)
      *(s16x8*)(ldsB + i*2048) = cvt8(pbf[i] + kt*32);
    __syncthreads();                       // staging complete (vmcnt+lgkmcnt)

    s16x8 af[4], bfr[4];
    #pragma unroll
    for (int m = 0; m < 4; ++m)
      af[m] = *(const s16x8*)(sA + (wr*64 + m*16 + l15)*32 + kg*8);
    #pragma unroll
    for (int n = 0; n < 4; ++n)
      bfr[n] = *(const s16x8*)(sB + (wc*64 + n*16 + l15)*32 + kg*8);
    #pragma unroll
    for (int m = 0; m < 4; ++m)
      #pragma unroll
      for (int n = 0; n < 4; ++n)
        acc[m][n] = __builtin_amdgcn_mfma_f32_16x16x32_bf16(
            __builtin_bit_cast(bf16x8, af[m]),
            __builtin_bit_cast(bf16x8, bfr[n]),
            acc[m][n], 0, 0, 0);
  }

  #pragma unroll
  for (int m = 0; m < 4; ++m){
    #pragma unroll
    for (int n = 0; n < 4; ++n){
      #pragma unroll
      for (int r = 0; r < 4; ++r){
        const int row = bm*128 + wr*64 + m*16 + kg*4 + r;
        const int col = bn*128 + wc*64 + n*16 + l15;
        float val = acc[m][n][r];
        if constexpr (MODE == 0){
          val = val * sigm(val);
          ((u16*)Cout)[(size_t)row*N + col] = f2bf(val);
        } else if constexpr (MODE == 1){
          val = sigm(val + bias[col]);
          ((u16*)Cout)[(size_t)row*N + col] = f2bf(val);
        } else if constexpr (MODE == 2){
          val = val + bias[col];
          ((u16*)Cout)[(size_t)row*N + col] = f2bf(val);
        } else {
          ((float*)Cout)[(size_t)row*N + col] = val;
        }
      }
    }
  }
}

// ---------------------------------------------------------------------------
// chunk-parallel linear scan: h_t = a_t * h_{t-1} + (1-a_t) * v_t
// ---------------------------------------------------------------------------
__global__ __launch_bounds__(256) void scan_pass1(
    const u16* __restrict__ alpha, const u16* __restrict__ v,
    float* __restrict__ P, float* __restrict__ H)
{
  const int e = blockIdx.x*256 + threadIdx.x;
  const int c = blockIdx.y;
  const size_t base = (size_t)c*CHUNK*EDIM + e;
  float p = 1.f, h = 0.f;
  #pragma unroll 8
  for (int t = 0; t < CHUNK; ++t){
    float a  = bf2f(alpha[base + (size_t)t*EDIM]);
    float vv = bf2f(v[base + (size_t)t*EDIM]);
    p *= a;
    h = a*h + (1.f - a)*vv;
  }
  P[(size_t)c*EDIM + e] = p;
  H[(size_t)c*EDIM + e] = h;
}

__global__ __launch_bounds__(256) void scan_pass2(
    const float* __restrict__ P, const float* __restrict__ H,
    const float* __restrict__ h0, float* __restrict__ hstart,
    float* __restrict__ hfinal)
{
  const int e = blockIdx.x*256 + threadIdx.x;
  float hs = h0[e];
  for (int c = 0; c < NCHUNK; ++c){
    hstart[(size_t)c*EDIM + e] = hs;
    hs = P[(size_t)c*EDIM + e]*hs + H[(size_t)c*EDIM + e];
  }
  hfinal[e] = hs;
}

__global__ __launch_bounds__(256) void scan_pass3(
    const u16* __restrict__ alpha, const u16* __restrict__ v,
    const float* __restrict__ hstart, u16* __restrict__ outs)
{
  const int e = blockIdx.x*256 + threadIdx.x;
  const int c = blockIdx.y;
  const size_t base = (size_t)c*CHUNK*EDIM + e;
  float h = hstart[(size_t)c*EDIM + e];
  #pragma unroll 8
  for (int t = 0; t < CHUNK; ++t){
    float a  = bf2f(alpha[base + (size_t)t*EDIM]);
    float vv = bf2f(v[base + (size_t)t*EDIM]);
    h = a*h + (1.f - a)*vv;
    float o = h*h*sigm(h);            // h * silu(h)
    outs[base + (size_t)t*EDIM] = f2bf(o);   // may alias v: write-after-read, same slot
  }
}

// ---------------------------------------------------------------------------
extern "C" void kernel_launch(void* const* d_in, const int* in_sizes, int n_in,
                              void* d_out, int out_size, void* d_ws, size_t ws_size,
                              hipStream_t stream)
{
  const float* x     = (const float*)d_in[0];
  const float* h0    = (const float*)d_in[1];
  const float* W_in  = (const float*)d_in[2];
  const float* W_al  = (const float*)d_in[3];
  const float* b_al  = (const float*)d_in[4];
  const float* W_v   = (const float*)d_in[5];
  const float* b_v   = (const float*)d_in[6];
  const float* W_out = (const float*)d_in[7];

  float* out  = (float*)d_out;
  float* hfin = out + (size_t)MROWS*D_MODEL;   // h_final tail of d_out

  // workspace layout (all 256B-aligned)
  const size_t SZ_ACT = (size_t)MROWS*D_INNER*2;   // 67,108,864 B
  const size_t SZ_ST  = (size_t)NCHUNK*EDIM*4;     //  4,194,304 B
  const size_t needed = 3*SZ_ACT + 3*SZ_ST;        // 213,909,504 B
  if (ws_size < needed) return;  // canary: clean fail (absmax = max|ref|) => ws too small

  char* ws = (char*)d_ws;
  auto carve = [&](size_t bytes){
    char* p = ws; ws += (bytes + 255) & ~(size_t)255; return p;
  };
  u16* xp   = (u16*)carve(SZ_ACT);   // silu(in_proj), layout [T, B*D_inner]
  u16* alp  = (u16*)carve(SZ_ACT);
  u16* vv   = (u16*)carve(SZ_ACT);   // v; pass3 overwrites in place with outs
  float* P  = (float*)carve(SZ_ST);
  float* H  = (float*)carve(SZ_ST);
  float* hs = (float*)carve(SZ_ST);

  gemm_bt<0, D_MODEL, D_INNER><<<dim3(MROWS/128, D_INNER/128), 256, 0, stream>>>(x,  W_in, nullptr, xp);
  gemm_bt<1, D_INNER, D_INNER><<<dim3(MROWS/128, D_INNER/128), 256, 0, stream>>>(xp, W_al, b_al,    alp);
  gemm_bt<2, D_INNER, D_INNER><<<dim3(MROWS/128, D_INNER/128), 256, 0, stream>>>(xp, W_v,  b_v,     vv);

  scan_pass1<<<dim3(EDIM/256, NCHUNK), 256, 0, stream>>>(alp, vv, P, H);
  scan_pass2<<<EDIM/256, 256, 0, stream>>>(P, H, h0, hs, hfin);
  scan_pass3<<<dim3(EDIM/256, NCHUNK), 256, 0, stream>>>(alp, vv, hs, vv);  // outs aliases vv

  gemm_bt<3, D_INNER, D_MODEL><<<dim3(MROWS/128, D_MODEL/128), 256, 0, stream>>>(vv, W_out, nullptr, out);
}